// Round 4
// baseline (280.797 us; speedup 1.0000x reference)
//
#include <hip/hip_runtime.h>
#include <hip/hip_bf16.h>

// Sizes
constexpr int BATCH = 8192;
constexpr int NREAL = 2000;   // real feature / output-col count
constexpr int KSLOT = 2048;   // per-matrix padded K slot
constexpr int KPAD  = 6144;   // 3 * 2048
constexpr int NPAD  = 2048;   // padded N (W_cat rows)
constexpr int NT    = KPAD / 32;  // 192 K-tiles of 32

typedef short bf16x8 __attribute__((ext_vector_type(8)));
typedef float f32x4  __attribute__((ext_vector_type(4)));

__device__ inline void gload_lds16(const void* g, void* l) {
  __builtin_amdgcn_global_load_lds(
      (const __attribute__((address_space(1))) unsigned int*)g,
      (__attribute__((address_space(3))) unsigned int*)l,
      16, 0, 0);
}

__device__ inline unsigned short f2bf(float x) {
  union { float f; unsigned int u; } v;
  v.f = x;
  unsigned int r = v.u + 0x7fffu + ((v.u >> 16) & 1u);
  return (unsigned short)(r >> 16);
}

// ---------------------------------------------------------------------------
// Kernel 1: fused pack. blockIdx.x < 8192: standardize (ddof=1) activations
// into A_cat [8192][6144]; else weight-concat rows into W_cat [2048][6144].
// grid (8192+2048, 3), block 256.
// ---------------------------------------------------------------------------
__global__ __launch_bounds__(256) void pack_kernel(
    const float* __restrict__ prev, const float* __restrict__ nxt,
    const float* __restrict__ selfa,
    const float* __restrict__ fW, const float* __restrict__ bW,
    const float* __restrict__ lW,
    unsigned short* __restrict__ Acat, unsigned short* __restrict__ Wcat) {
  const int mat = blockIdx.y;
  const int t = threadIdx.x;

  if (blockIdx.x >= BATCH) {
    // ---- weight pack ----
    const int s = blockIdx.x - BATCH;
    uint4 q = make_uint4(0, 0, 0, 0);
    if (s < NREAL && t < 250) {
      const float* src = ((mat == 0) ? fW : (mat == 1) ? bW : lW) +
                         (size_t)s * NREAL + t * 8;
      const float4* p = (const float4*)src;
      float4 a = p[0], b = p[1];
      q.x = (unsigned)f2bf(a.x) | ((unsigned)f2bf(a.y) << 16);
      q.y = (unsigned)f2bf(a.z) | ((unsigned)f2bf(a.w) << 16);
      q.z = (unsigned)f2bf(b.x) | ((unsigned)f2bf(b.y) << 16);
      q.w = (unsigned)f2bf(b.z) | ((unsigned)f2bf(b.w) << 16);
    }
    *(uint4*)(Wcat + (size_t)s * KPAD + mat * KSLOT + t * 8) = q;
    return;
  }

  // ---- standardize pack ----
  __shared__ float red[4];
  const int row = blockIdx.x;
  const float* src = (mat == 0) ? prev : (mat == 1) ? nxt : selfa;

  float x[8];
  float s1 = 0.f;
  if (t < 250) {
    const float4* p = (const float4*)(src + (size_t)row * NREAL + t * 8);
    float4 a = p[0], b = p[1];
    x[0] = a.x; x[1] = a.y; x[2] = a.z; x[3] = a.w;
    x[4] = b.x; x[5] = b.y; x[6] = b.z; x[7] = b.w;
#pragma unroll
    for (int j = 0; j < 8; ++j) s1 += x[j];
  } else {
#pragma unroll
    for (int j = 0; j < 8; ++j) x[j] = 0.f;
  }
#pragma unroll
  for (int o = 32; o; o >>= 1) s1 += __shfl_xor(s1, o);
  if ((t & 63) == 0) red[t >> 6] = s1;
  __syncthreads();
  const float mean = (red[0] + red[1] + red[2] + red[3]) * (1.f / 2000.f);
  __syncthreads();

  float ss = 0.f;
  if (t < 250) {
#pragma unroll
    for (int j = 0; j < 8; ++j) { float d = x[j] - mean; ss += d * d; }
  }
#pragma unroll
  for (int o = 32; o; o >>= 1) ss += __shfl_xor(ss, o);
  if ((t & 63) == 0) red[t >> 6] = ss;
  __syncthreads();
  const float var = (red[0] + red[1] + red[2] + red[3]) * (1.f / 1999.f);
  const float scale = 1.f / (sqrtf(var) + 1e-8f);

  unsigned short o8[8];
  if (t < 250) {
#pragma unroll
    for (int j = 0; j < 8; ++j) o8[j] = f2bf((x[j] - mean) * scale);
  } else {
#pragma unroll
    for (int j = 0; j < 8; ++j) o8[j] = 0;
  }
  uint4 q;
  q.x = (unsigned)o8[0] | ((unsigned)o8[1] << 16);
  q.y = (unsigned)o8[2] | ((unsigned)o8[3] << 16);
  q.z = (unsigned)o8[4] | ((unsigned)o8[5] << 16);
  q.w = (unsigned)o8[6] | ((unsigned)o8[7] << 16);
  *(uint4*)(Acat + (size_t)row * KPAD + mat * KSLOT + t * 8) = q;
}

// ---------------------------------------------------------------------------
// Kernel 2: BM=128 x BN=256 x BK=32 bf16 MFMA GEMM, 4 waves (each 128x64 out),
// TRIPLE-buffered LDS (3 x 24KB = 72KB) -> 2 independent blocks/CU for
// cross-block stall hiding. 2 phases/K-tile, 16 MFMA/phase/wave.
// Stage lookahead = 2 tiles; counted vmcnt(3) once per tile (never 0 until
// the last 2 tiles). XOR-swizzled 16B chunks (0 conflicts, both sides).
// XCD swizzle: bn = blockIdx&7 pins one 3.1MB B-panel per XCD L2.
// grid 512 (= 64 bm x 8 bn), block 256.
// ---------------------------------------------------------------------------
__global__ __launch_bounds__(256, 2) void gemm_kernel(
    const unsigned short* __restrict__ A,   // [8192][6144] bf16
    const unsigned short* __restrict__ W,   // [2048][6144] bf16
    const float* __restrict__ fbv, const float* __restrict__ bbv,
    const float* __restrict__ lbv,
    const float* __restrict__ selfact,      // [8192][2000] f32
    float* __restrict__ out) {              // [8192][2000] f32
  __shared__ unsigned short lds[3 * 12288];  // per buf: A[128][32] + B[256][32]
  unsigned short* ldsF = lds;

  const int tid  = threadIdx.x;
  const int wave = tid >> 6;
  const int lane = tid & 63;
  const int wn = wave;          // 0..3 (N split); all waves share full 128 rows

  const int bn = blockIdx.x & 7;    // XCD-pinned B panel
  const int bm = blockIdx.x >> 3;   // 0..63

  // staging per-thread source (inverse swizzle): row=tid>>2, chunk=tid&3
  const int srow = tid >> 2;
  const int sc = (tid & 3) ^ ((srow >> 1) & 3);
  const unsigned short* Asrc = A + (size_t)(bm * 128 + srow) * KPAD + sc * 8;
  const unsigned short* Bsrc = W + (size_t)(bn * 256 + srow) * KPAD + sc * 8;

  // fragment read bases (swizzle folds to per-lane constant)
  const int pcx = (lane >> 4) ^ ((lane >> 1) & 3);
  const unsigned short* aFb = ldsF + (lane & 15) * 32 + pcx * 8;
  const unsigned short* bFb = ldsF + 4096 + (wn * 64 + (lane & 15)) * 32 + pcx * 8;

  f32x4 acc[8][4] = {};
  bf16x8 afA[4], afB[4], bf[4];

  // A-tile: 8KB = 2 gload calls/thread; B-tile: 16KB = 4 calls (split 1+3)
#define STAGE_A(qq, tt) { \
    const unsigned short* g_ = Asrc + (size_t)(tt) * 32; \
    unsigned short* d_ = ldsF + (qq) * 12288 + wave * 512; \
    gload_lds16(g_, d_); \
    gload_lds16(g_ + (size_t)64 * KPAD, d_ + 2048); \
  }
#define STAGE_B1(qq, tt) { \
    const unsigned short* g_ = Bsrc + (size_t)(tt) * 32; \
    unsigned short* d_ = ldsF + (qq) * 12288 + 4096 + wave * 512; \
    gload_lds16(g_, d_); \
  }
#define STAGE_B2(qq, tt) { \
    const unsigned short* g_ = Bsrc + (size_t)(tt) * 32 + (size_t)64 * KPAD; \
    unsigned short* d_ = ldsF + (qq) * 12288 + 4096 + 2048 + wave * 512; \
    gload_lds16(g_, d_); \
    gload_lds16(g_ + (size_t)64 * KPAD, d_ + 2048); \
    gload_lds16(g_ + (size_t)128 * KPAD, d_ + 4096); \
  }

#define READ_AF(dst, qq, mh) \
    _Pragma("unroll") for (int fm = 0; fm < 4; ++fm) \
      dst[fm] = *(const bf16x8*)(aFb + (qq) * 12288 + ((mh) * 4 + fm) * 512);
#define READ_BF(dst, qq) \
    _Pragma("unroll") for (int fn = 0; fn < 4; ++fn) \
      dst[fn] = *(const bf16x8*)(bFb + (qq) * 12288 + fn * 512);

#define MFMA16(afr, bfr, mh) { \
    __builtin_amdgcn_s_setprio(1); \
    _Pragma("unroll") for (int fm = 0; fm < 4; ++fm) \
    _Pragma("unroll") for (int fn = 0; fn < 4; ++fn) \
      acc[(mh) * 4 + fm][fn] = __builtin_amdgcn_mfma_f32_16x16x32_bf16( \
          afr[fm], bfr[fn], acc[(mh) * 4 + fm][fn], 0, 0, 0); \
    __builtin_amdgcn_s_setprio(0); \
  }

  // ph1(t): reads bf(t)+afB(t,mh1) (same-phase bf use, lgkm-waited);
  //         stages t+2 part1 (A x2 + B x1); MFMA(afA, bf, mh0).
  // ph2(t): vmcnt(3) [t+1 fully landed]; barrier; reads afA(t+1, mh0);
  //         stages t+2 part2 (B x3); MFMA(afB, bf, mh1).
#define PH1(q, t, DS) { \
    __builtin_amdgcn_s_barrier(); \
    __builtin_amdgcn_sched_barrier(0); \
    READ_BF(bf, q) \
    READ_AF(afB, q, 1) \
    if (DS) { STAGE_A((((q) + 2) % 3), (t) + 2) STAGE_B1((((q) + 2) % 3), (t) + 2) } \
    MFMA16(afA, bf, 0) \
  }
#define PH2(q, t, VM, DS, RN) { \
    asm volatile("s_waitcnt vmcnt(" VM ")" ::: "memory"); \
    __builtin_amdgcn_s_barrier(); \
    __builtin_amdgcn_sched_barrier(0); \
    if (RN) { READ_AF(afA, (((q) + 1) % 3), 0) } \
    if (DS) { STAGE_B2((((q) + 2) % 3), (t) + 2) } \
    MFMA16(afB, bf, 1) \
  }

  // Prologue: stage tiles 0 and 1 (6 loads each); wait tile 0; read afA(t0).
  STAGE_A(0, 0) STAGE_B1(0, 0) STAGE_B2(0, 0)
  STAGE_A(1, 1) STAGE_B1(1, 1) STAGE_B2(1, 1)
  asm volatile("s_waitcnt vmcnt(6)" ::: "memory");
  __builtin_amdgcn_s_barrier();
  __builtin_amdgcn_sched_barrier(0);
  READ_AF(afA, 0, 0)

  // Steady: t = 0..188 (63 x 3 tiles), then tail 189/190/191.
  for (int i = 0; i < 63; ++i) {
    const int t = i * 3;
    PH1(0, t, true)     PH2(0, t, "3", true, true)
    PH1(1, t + 1, true) PH2(1, t + 1, "3", true, true)
    PH1(2, t + 2, true) PH2(2, t + 2, "3", true, true)
  }
  PH1(0, 189, true)  PH2(0, 189, "3", true, true)
  PH1(1, 190, false) PH2(1, 190, "0", false, true)
  PH1(2, 191, false) PH2(2, 191, "0", false, false)

  // Epilogue: C/D layout col=lane&15, row=(lane>>4)*4+reg
  const int colLane = lane & 15;
  const int rowGrp  = (lane >> 4) * 4;
#pragma unroll
  for (int fn = 0; fn < 4; ++fn) {
    const int col = bn * 256 + wn * 64 + fn * 16 + colLane;
    if (col < NREAL) {
      const float bias = fbv[col] + bbv[col] + lbv[col];
#pragma unroll
      for (int m = 0; m < 8; ++m) {
        const int row0 = bm * 128 + m * 16 + rowGrp;
#pragma unroll
        for (int r = 0; r < 4; ++r) {
          const float pre = acc[m][fn][r] + bias;
          const size_t oi = (size_t)(row0 + r) * NREAL + col;
          out[oi] = 0.7f * fmaxf(pre, 0.f) + 0.3f * selfact[oi];
        }
      }
    }
  }
#undef PH2
#undef PH1
#undef MFMA16
#undef READ_BF
#undef READ_AF
#undef STAGE_B2
#undef STAGE_B1
#undef STAGE_A
}

// ---------------------------------------------------------------------------
extern "C" void kernel_launch(void* const* d_in, const int* in_sizes, int n_in,
                              void* d_out, int out_size, void* d_ws,
                              size_t ws_size, hipStream_t stream) {
  const float* prev = (const float*)d_in[0];
  const float* selfa = (const float*)d_in[1];
  const float* nxt  = (const float*)d_in[2];
  const float* fW = (const float*)d_in[3];
  const float* fb = (const float*)d_in[4];
  const float* bW = (const float*)d_in[5];
  const float* bb = (const float*)d_in[6];
  const float* lW = (const float*)d_in[7];
  const float* lb = (const float*)d_in[8];
  float* out = (float*)d_out;

  unsigned short* Acat = (unsigned short*)d_ws;                 // 100.7 MB
  unsigned short* Wcat = Acat + (size_t)BATCH * KPAD;           // +25.2 MB

  pack_kernel<<<dim3(BATCH + NPAD, 3), 256, 0, stream>>>(
      prev, nxt, selfa, fW, bW, lW, Acat, Wcat);
  gemm_kernel<<<dim3(64 * 8), 256, 0, stream>>>(Acat, Wcat, fb, bb, lb,
                                                selfa, out);
}

// Round 5
// 276.530 us; speedup vs baseline: 1.0154x; 1.0154x over previous
//
#include <hip/hip_runtime.h>
#include <hip/hip_bf16.h>

// Sizes
constexpr int BATCH = 8192;
constexpr int NREAL = 2000;   // real feature / output-col count
constexpr int KSLOT = 2048;   // per-matrix padded K slot
constexpr int KPAD  = 6144;   // 3 * 2048
constexpr int NPAD  = 2048;   // padded N (W_cat rows)
constexpr int NT    = KPAD / 64;  // 96 K-tiles of 64

typedef short bf16x8 __attribute__((ext_vector_type(8)));
typedef float f32x4  __attribute__((ext_vector_type(4)));

__device__ inline void gload_lds16(const void* g, void* l) {
  __builtin_amdgcn_global_load_lds(
      (const __attribute__((address_space(1))) unsigned int*)g,
      (__attribute__((address_space(3))) unsigned int*)l,
      16, 0, 0);
}

__device__ inline unsigned short f2bf(float x) {
  union { float f; unsigned int u; } v;
  v.f = x;
  unsigned int r = v.u + 0x7fffu + ((v.u >> 16) & 1u);
  return (unsigned short)(r >> 16);
}

// ---------------------------------------------------------------------------
// Kernel 1: fused pack. blockIdx.x < 8192: standardize (ddof=1) activations
// into A_cat [8192][6144]; else weight-concat rows into W_cat [2048][6144].
// grid (8192+2048, 3), block 256.
// ---------------------------------------------------------------------------
__global__ __launch_bounds__(256) void pack_kernel(
    const float* __restrict__ prev, const float* __restrict__ nxt,
    const float* __restrict__ selfa,
    const float* __restrict__ fW, const float* __restrict__ bW,
    const float* __restrict__ lW,
    unsigned short* __restrict__ Acat, unsigned short* __restrict__ Wcat) {
  const int mat = blockIdx.y;
  const int t = threadIdx.x;

  if (blockIdx.x >= BATCH) {
    // ---- weight pack ----
    const int s = blockIdx.x - BATCH;
    uint4 q = make_uint4(0, 0, 0, 0);
    if (s < NREAL && t < 250) {
      const float* src = ((mat == 0) ? fW : (mat == 1) ? bW : lW) +
                         (size_t)s * NREAL + t * 8;
      const float4* p = (const float4*)src;
      float4 a = p[0], b = p[1];
      q.x = (unsigned)f2bf(a.x) | ((unsigned)f2bf(a.y) << 16);
      q.y = (unsigned)f2bf(a.z) | ((unsigned)f2bf(a.w) << 16);
      q.z = (unsigned)f2bf(b.x) | ((unsigned)f2bf(b.y) << 16);
      q.w = (unsigned)f2bf(b.z) | ((unsigned)f2bf(b.w) << 16);
    }
    *(uint4*)(Wcat + (size_t)s * KPAD + mat * KSLOT + t * 8) = q;
    return;
  }

  // ---- standardize pack ----
  __shared__ float red[4];
  const int row = blockIdx.x;
  const float* src = (mat == 0) ? prev : (mat == 1) ? nxt : selfa;

  float x[8];
  float s1 = 0.f;
  if (t < 250) {
    const float4* p = (const float4*)(src + (size_t)row * NREAL + t * 8);
    float4 a = p[0], b = p[1];
    x[0] = a.x; x[1] = a.y; x[2] = a.z; x[3] = a.w;
    x[4] = b.x; x[5] = b.y; x[6] = b.z; x[7] = b.w;
#pragma unroll
    for (int j = 0; j < 8; ++j) s1 += x[j];
  } else {
#pragma unroll
    for (int j = 0; j < 8; ++j) x[j] = 0.f;
  }
#pragma unroll
  for (int o = 32; o; o >>= 1) s1 += __shfl_xor(s1, o);
  if ((t & 63) == 0) red[t >> 6] = s1;
  __syncthreads();
  const float mean = (red[0] + red[1] + red[2] + red[3]) * (1.f / 2000.f);
  __syncthreads();

  float ss = 0.f;
  if (t < 250) {
#pragma unroll
    for (int j = 0; j < 8; ++j) { float d = x[j] - mean; ss += d * d; }
  }
#pragma unroll
  for (int o = 32; o; o >>= 1) ss += __shfl_xor(ss, o);
  if ((t & 63) == 0) red[t >> 6] = ss;
  __syncthreads();
  const float var = (red[0] + red[1] + red[2] + red[3]) * (1.f / 1999.f);
  const float scale = 1.f / (sqrtf(var) + 1e-8f);

  unsigned short o8[8];
  if (t < 250) {
#pragma unroll
    for (int j = 0; j < 8; ++j) o8[j] = f2bf((x[j] - mean) * scale);
  } else {
#pragma unroll
    for (int j = 0; j < 8; ++j) o8[j] = 0;
  }
  uint4 q;
  q.x = (unsigned)o8[0] | ((unsigned)o8[1] << 16);
  q.y = (unsigned)o8[2] | ((unsigned)o8[3] << 16);
  q.z = (unsigned)o8[4] | ((unsigned)o8[5] << 16);
  q.w = (unsigned)o8[6] | ((unsigned)o8[7] << 16);
  *(uint4*)(Acat + (size_t)row * KPAD + mat * KSLOT + t * 8) = q;
}

// ---------------------------------------------------------------------------
// Kernel 2: 256x256 bf16 MFMA GEMM, BK=64, 8 waves (2M x 4N), 2-buf LDS,
// register-subtile pipelining (all ds_reads one phase ahead of use) and
// DEEP-COVERAGE counted vmcnt: stages issued at ph1(A-h0+B-h0,t+1),
// ph2(A-h1), ph3(B-h1); waits vmcnt(4) at ph2 (forces Ah1/Bh1(t), issued
// 3-4 phases back) and ph4 (forces Ah0/Bh0(t+1), issued 3 phases back).
// No 1-phase-old load is ever forced -> HBM/L2 latency fully covered.
// XOR-swizzled 16B chunks both sides (0 bank conflicts). Fused epilogue.
// grid 256 (= 32 bm x 8 bn), block 512.
// ---------------------------------------------------------------------------
__global__ __launch_bounds__(512, 2) void gemm_kernel(
    const unsigned short* __restrict__ A,   // [8192][6144] bf16
    const unsigned short* __restrict__ W,   // [2048][6144] bf16
    const float* __restrict__ fb, const float* __restrict__ bb,
    const float* __restrict__ lb,
    const float* __restrict__ selfact,      // [8192][2000] f32
    float* __restrict__ out) {              // [8192][2000] f32
  __shared__ unsigned short lds[2][2][2][256][32];  // 128 KiB
  unsigned short* ldsF = &lds[0][0][0][0][0];

  const int tid  = threadIdx.x;
  const int wave = tid >> 6;
  const int lane = tid & 63;
  const int wm = wave >> 2;     // 0..1
  const int wn = wave & 3;      // 0..3

  // XCD-aware block swizzle (256 blocks, 8 XCDs, 32/XCD, 4 bm-panels each)
  const int nbid = (blockIdx.x & 7) * 32 + (blockIdx.x >> 3);
  const int bm = nbid >> 3;     // 0..31
  const int bn = nbid & 7;      // 0..7

  // staging per-thread source (inverse swizzle): row=tid>>2, pc=tid&3
  const int srow = tid >> 2;
  const int sc = (tid & 3) ^ ((srow >> 1) & 3);
  const unsigned short* Asrc =
      A + (size_t)(bm * 256 + srow) * KPAD + sc * 8;
  const unsigned short* Bsrc =
      W + (size_t)(bn * 256 + srow) * KPAD + sc * 8;

  // fragment read bases (swizzle folds to per-lane constant)
  const int pcx = (lane >> 4) ^ ((lane >> 1) & 3);
  const unsigned short* aF = ldsF + (wm * 128 + (lane & 15)) * 32 + pcx * 8;
  const unsigned short* bF = ldsF + (wn * 64 + (lane & 15)) * 32 + pcx * 8;

  f32x4 acc[8][4] = {};
  bf16x8 afA[4], afB[4], bf0[4], bf1[4];

#define STAGE(sb, mat, h, tt) { \
    const unsigned short* g_ = ((mat) ? Bsrc : Asrc) + (size_t)(tt) * 64 + (h) * 32; \
    unsigned short* d_ = ldsF + ((sb) * 4 + (mat) * 2 + (h)) * 8192 + wave * 64 * 8; \
    gload_lds16(g_, d_); \
    gload_lds16(g_ + (size_t)128 * KPAD, d_ + 512 * 8); \
  }

#define READ_AF(dst, bb, kk, mh) \
    _Pragma("unroll") for (int fm = 0; fm < 4; ++fm) \
      dst[fm] = *(const bf16x8*)(aF + ((bb) * 4 + (kk)) * 8192 + ((mh) * 64 + fm * 16) * 32);

#define READ_BF(dst, bb, kk) \
    _Pragma("unroll") for (int fn = 0; fn < 4; ++fn) \
      dst[fn] = *(const bf16x8*)(bF + ((bb) * 4 + 2 + (kk)) * 8192 + (fn * 16) * 32);

#define MFMA16(afr, bfr, mh) { \
    __builtin_amdgcn_s_setprio(1); \
    _Pragma("unroll") for (int fm = 0; fm < 4; ++fm) \
    _Pragma("unroll") for (int fn = 0; fn < 4; ++fn) \
      acc[(mh) * 4 + fm][fn] = __builtin_amdgcn_mfma_f32_16x16x32_bf16( \
          afr[fm], bfr[fn], acc[(mh) * 4 + fm][fn], 0, 0, 0); \
    __builtin_amdgcn_s_setprio(0); \
  }

  // ---- 4-phase tile, deep-coverage waits ----
#define PH1(b, t, DS) { \
    __builtin_amdgcn_s_barrier(); \
    __builtin_amdgcn_sched_barrier(0); \
    READ_AF(afB, b, 0, 1) \
    if (DS) { STAGE((b) ^ 1, 0, 0, (t) + 1) STAGE((b) ^ 1, 1, 0, (t) + 1) } \
    MFMA16(afA, bf0, 0) \
  }
#define PH2(b, t, VM, DS) { \
    asm volatile("s_waitcnt vmcnt(" VM ")" ::: "memory"); \
    __builtin_amdgcn_s_barrier(); \
    __builtin_amdgcn_sched_barrier(0); \
    READ_AF(afA, b, 1, 0) \
    READ_BF(bf1, b, 1) \
    if (DS) { STAGE((b) ^ 1, 0, 1, (t) + 1) } \
    MFMA16(afB, bf0, 1) \
  }
#define PH3(b, t, DS) { \
    __builtin_amdgcn_s_barrier(); \
    __builtin_amdgcn_sched_barrier(0); \
    READ_AF(afB, b, 1, 1) \
    if (DS) { STAGE((b) ^ 1, 1, 1, (t) + 1) } \
    MFMA16(afA, bf1, 0) \
  }
#define PH4(b, VM, RN) { \
    asm volatile("s_waitcnt vmcnt(" VM ")" ::: "memory"); \
    __builtin_amdgcn_s_barrier(); \
    __builtin_amdgcn_sched_barrier(0); \
    if (RN) { READ_AF(afA, (b) ^ 1, 0, 0) READ_BF(bf0, (b) ^ 1, 0) } \
    MFMA16(afB, bf1, 1) \
  }

  // Prologue: stage all of tile 0 (8 calls); wait its h0; read ph1 regs.
  // FIFO invariant at loop entry: pending = [Ah1(0), Bh1(0)] = 4.
  STAGE(0, 0, 0, 0)   // A h0 (t0)
  STAGE(0, 1, 0, 0)   // B h0 (t0)
  STAGE(0, 0, 1, 0)   // A h1 (t0)
  STAGE(0, 1, 1, 0)   // B h1 (t0)
  asm volatile("s_waitcnt vmcnt(4)" ::: "memory");  // t0 h0 landed
  __builtin_amdgcn_s_barrier();
  __builtin_amdgcn_sched_barrier(0);
  READ_AF(afA, 0, 0, 0)
  READ_BF(bf0, 0, 0)

  for (int t = 0; t < NT - 1; ++t) {
    const int b = t & 1;
    PH1(b, t, true)
    PH2(b, t, "4", true)
    PH3(b, t, true)
    PH4(b, "4", true)
  }
  // last tile (t = NT-1, b = 1): no staging; drain.
  PH1(1, NT - 1, false)
  PH2(1, NT - 1, "0", false)
  PH3(1, NT - 1, false)
  PH4(1, "0", false)

  // Epilogue: C/D layout col=lane&15, row=(lane>>4)*4+reg
  const int colLane = lane & 15;
  const int rowGrp  = (lane >> 4) * 4;
#pragma unroll
  for (int fn = 0; fn < 4; ++fn) {
    const int col = bn * 256 + wn * 64 + fn * 16 + colLane;
    if (col < NREAL) {
      const float bias = fb[col] + bb[col] + lb[col];
#pragma unroll
      for (int m = 0; m < 8; ++m) {
        const int row0 = bm * 256 + wm * 128 + m * 16 + rowGrp;
#pragma unroll
        for (int r = 0; r < 4; ++r) {
          const float pre = acc[m][fn][r] + bias;
          const size_t oi = (size_t)(row0 + r) * NREAL + col;
          out[oi] = 0.7f * fmaxf(pre, 0.f) + 0.3f * selfact[oi];
        }
      }
    }
  }
#undef PH4
#undef PH3
#undef PH2
#undef PH1
#undef MFMA16
#undef READ_BF
#undef READ_AF
#undef STAGE
}

// ---------------------------------------------------------------------------
extern "C" void kernel_launch(void* const* d_in, const int* in_sizes, int n_in,
                              void* d_out, int out_size, void* d_ws,
                              size_t ws_size, hipStream_t stream) {
  const float* prev = (const float*)d_in[0];
  const float* selfa = (const float*)d_in[1];
  const float* nxt  = (const float*)d_in[2];
  const float* fW = (const float*)d_in[3];
  const float* fb = (const float*)d_in[4];
  const float* bW = (const float*)d_in[5];
  const float* bb = (const float*)d_in[6];
  const float* lW = (const float*)d_in[7];
  const float* lb = (const float*)d_in[8];
  float* out = (float*)d_out;

  unsigned short* Acat = (unsigned short*)d_ws;                 // 100.7 MB
  unsigned short* Wcat = Acat + (size_t)BATCH * KPAD;           // +25.2 MB

  pack_kernel<<<dim3(BATCH + NPAD, 3), 256, 0, stream>>>(
      prev, nxt, selfa, fW, bW, lW, Acat, Wcat);
  gemm_kernel<<<dim3(32 * 8), 512, 0, stream>>>(Acat, Wcat, fb, bb, lb,
                                                selfa, out);
}

// Round 6
// 268.551 us; speedup vs baseline: 1.0456x; 1.0297x over previous
//
#include <hip/hip_runtime.h>
#include <hip/hip_bf16.h>

// Sizes
constexpr int BATCH = 8192;
constexpr int NREAL = 2000;   // real feature / output-col count
constexpr int KSLOT = 2048;   // per-matrix padded K slot
constexpr int KPAD  = 6144;   // 3 * 2048
constexpr int NPAD  = 2048;   // padded N (W_cat rows)
constexpr int NT    = KPAD / 64;  // 96 K-tiles of 64

typedef short bf16x8 __attribute__((ext_vector_type(8)));
typedef float f32x4  __attribute__((ext_vector_type(4)));

__device__ inline void gload_lds16(const void* g, void* l) {
  __builtin_amdgcn_global_load_lds(
      (const __attribute__((address_space(1))) unsigned int*)g,
      (__attribute__((address_space(3))) unsigned int*)l,
      16, 0, 0);
}

__device__ inline unsigned short f2bf(float x) {
  union { float f; unsigned int u; } v;
  v.f = x;
  unsigned int r = v.u + 0x7fffu + ((v.u >> 16) & 1u);
  return (unsigned short)(r >> 16);
}

// ---------------------------------------------------------------------------
// Kernel 1: fused pack. blockIdx.x < 8192: standardize (ddof=1) activations
// into A_cat [8192][6144]; else weight-concat rows into W_cat [2048][6144].
// grid (8192+2048, 3), block 256.
// ---------------------------------------------------------------------------
__global__ __launch_bounds__(256) void pack_kernel(
    const float* __restrict__ prev, const float* __restrict__ nxt,
    const float* __restrict__ selfa,
    const float* __restrict__ fW, const float* __restrict__ bW,
    const float* __restrict__ lW,
    unsigned short* __restrict__ Acat, unsigned short* __restrict__ Wcat) {
  const int mat = blockIdx.y;
  const int t = threadIdx.x;

  if (blockIdx.x >= BATCH) {
    // ---- weight pack ----
    const int s = blockIdx.x - BATCH;
    uint4 q = make_uint4(0, 0, 0, 0);
    if (s < NREAL && t < 250) {
      const float* src = ((mat == 0) ? fW : (mat == 1) ? bW : lW) +
                         (size_t)s * NREAL + t * 8;
      const float4* p = (const float4*)src;
      float4 a = p[0], b = p[1];
      q.x = (unsigned)f2bf(a.x) | ((unsigned)f2bf(a.y) << 16);
      q.y = (unsigned)f2bf(a.z) | ((unsigned)f2bf(a.w) << 16);
      q.z = (unsigned)f2bf(b.x) | ((unsigned)f2bf(b.y) << 16);
      q.w = (unsigned)f2bf(b.z) | ((unsigned)f2bf(b.w) << 16);
    }
    *(uint4*)(Wcat + (size_t)s * KPAD + mat * KSLOT + t * 8) = q;
    return;
  }

  // ---- standardize pack ----
  __shared__ float red[4];
  const int row = blockIdx.x;
  const float* src = (mat == 0) ? prev : (mat == 1) ? nxt : selfa;

  float x[8];
  float s1 = 0.f;
  if (t < 250) {
    const float4* p = (const float4*)(src + (size_t)row * NREAL + t * 8);
    float4 a = p[0], b = p[1];
    x[0] = a.x; x[1] = a.y; x[2] = a.z; x[3] = a.w;
    x[4] = b.x; x[5] = b.y; x[6] = b.z; x[7] = b.w;
#pragma unroll
    for (int j = 0; j < 8; ++j) s1 += x[j];
  } else {
#pragma unroll
    for (int j = 0; j < 8; ++j) x[j] = 0.f;
  }
#pragma unroll
  for (int o = 32; o; o >>= 1) s1 += __shfl_xor(s1, o);
  if ((t & 63) == 0) red[t >> 6] = s1;
  __syncthreads();
  const float mean = (red[0] + red[1] + red[2] + red[3]) * (1.f / 2000.f);
  __syncthreads();

  float ss = 0.f;
  if (t < 250) {
#pragma unroll
    for (int j = 0; j < 8; ++j) { float d = x[j] - mean; ss += d * d; }
  }
#pragma unroll
  for (int o = 32; o; o >>= 1) ss += __shfl_xor(ss, o);
  if ((t & 63) == 0) red[t >> 6] = ss;
  __syncthreads();
  const float var = (red[0] + red[1] + red[2] + red[3]) * (1.f / 1999.f);
  const float scale = 1.f / (sqrtf(var) + 1e-8f);

  unsigned short o8[8];
  if (t < 250) {
#pragma unroll
    for (int j = 0; j < 8; ++j) o8[j] = f2bf((x[j] - mean) * scale);
  } else {
#pragma unroll
    for (int j = 0; j < 8; ++j) o8[j] = 0;
  }
  uint4 q;
  q.x = (unsigned)o8[0] | ((unsigned)o8[1] << 16);
  q.y = (unsigned)o8[2] | ((unsigned)o8[3] << 16);
  q.z = (unsigned)o8[4] | ((unsigned)o8[5] << 16);
  q.w = (unsigned)o8[6] | ((unsigned)o8[7] << 16);
  *(uint4*)(Acat + (size_t)row * KPAD + mat * KSLOT + t * 8) = q;
}

// ---------------------------------------------------------------------------
// Kernel 2: 256x256 bf16 MFMA GEMM, BK=64, 8 waves (2M x 4N), 2-buf LDS,
// register-subtile pipelining + deep-coverage counted vmcnt (as R5), but
// sched_barrier(0) ONLY after the two vmcnt-publication barriers (ph2/ph4).
// ph1/ph3 are unpinned so the compiler can overlap their ds_reads/MFMAs
// across phase boundaries (m141 lesson: full pinning defeats scheduling).
// XOR-swizzled 16B chunks both sides (0 bank conflicts). Fused epilogue.
// grid 256 (= 32 bm x 8 bn), block 512.
// ---------------------------------------------------------------------------
__global__ __launch_bounds__(512, 2) void gemm_kernel(
    const unsigned short* __restrict__ A,   // [8192][6144] bf16
    const unsigned short* __restrict__ W,   // [2048][6144] bf16
    const float* __restrict__ fb, const float* __restrict__ bb,
    const float* __restrict__ lb,
    const float* __restrict__ selfact,      // [8192][2000] f32
    float* __restrict__ out) {              // [8192][2000] f32
  __shared__ unsigned short lds[2][2][2][256][32];  // 128 KiB
  unsigned short* ldsF = &lds[0][0][0][0][0];

  const int tid  = threadIdx.x;
  const int wave = tid >> 6;
  const int lane = tid & 63;
  const int wm = wave >> 2;     // 0..1
  const int wn = wave & 3;      // 0..3

  // XCD-aware block swizzle (256 blocks, 8 XCDs, 32/XCD, 4 bm-panels each)
  const int nbid = (blockIdx.x & 7) * 32 + (blockIdx.x >> 3);
  const int bm = nbid >> 3;     // 0..31
  const int bn = nbid & 7;      // 0..7

  // staging per-thread source (inverse swizzle): row=tid>>2, pc=tid&3
  const int srow = tid >> 2;
  const int sc = (tid & 3) ^ ((srow >> 1) & 3);
  const unsigned short* Asrc =
      A + (size_t)(bm * 256 + srow) * KPAD + sc * 8;
  const unsigned short* Bsrc =
      W + (size_t)(bn * 256 + srow) * KPAD + sc * 8;

  // fragment read bases (swizzle folds to per-lane constant)
  const int pcx = (lane >> 4) ^ ((lane >> 1) & 3);
  const unsigned short* aF = ldsF + (wm * 128 + (lane & 15)) * 32 + pcx * 8;
  const unsigned short* bF = ldsF + (wn * 64 + (lane & 15)) * 32 + pcx * 8;

  f32x4 acc[8][4] = {};
  bf16x8 afA[4], afB[4], bf0[4], bf1[4];

#define STAGE(sb, mat, h, tt) { \
    const unsigned short* g_ = ((mat) ? Bsrc : Asrc) + (size_t)(tt) * 64 + (h) * 32; \
    unsigned short* d_ = ldsF + ((sb) * 4 + (mat) * 2 + (h)) * 8192 + wave * 64 * 8; \
    gload_lds16(g_, d_); \
    gload_lds16(g_ + (size_t)128 * KPAD, d_ + 512 * 8); \
  }

#define READ_AF(dst, bb, kk, mh) \
    _Pragma("unroll") for (int fm = 0; fm < 4; ++fm) \
      dst[fm] = *(const bf16x8*)(aF + ((bb) * 4 + (kk)) * 8192 + ((mh) * 64 + fm * 16) * 32);

#define READ_BF(dst, bb, kk) \
    _Pragma("unroll") for (int fn = 0; fn < 4; ++fn) \
      dst[fn] = *(const bf16x8*)(bF + ((bb) * 4 + 2 + (kk)) * 8192 + (fn * 16) * 32);

#define MFMA16(afr, bfr, mh) { \
    __builtin_amdgcn_s_setprio(1); \
    _Pragma("unroll") for (int fm = 0; fm < 4; ++fm) \
    _Pragma("unroll") for (int fn = 0; fn < 4; ++fn) \
      acc[(mh) * 4 + fm][fn] = __builtin_amdgcn_mfma_f32_16x16x32_bf16( \
          afr[fm], bfr[fn], acc[(mh) * 4 + fm][fn], 0, 0, 0); \
    __builtin_amdgcn_s_setprio(0); \
  }

  // ---- 4-phase tile. sched_barrier(0) only at publication points (ph2/ph4).
#define PH1(b, t, DS) { \
    __builtin_amdgcn_s_barrier(); \
    READ_AF(afB, b, 0, 1) \
    if (DS) { STAGE((b) ^ 1, 0, 0, (t) + 1) STAGE((b) ^ 1, 1, 0, (t) + 1) } \
    MFMA16(afA, bf0, 0) \
  }
#define PH2(b, t, VM, DS) { \
    asm volatile("s_waitcnt vmcnt(" VM ")" ::: "memory"); \
    __builtin_amdgcn_s_barrier(); \
    __builtin_amdgcn_sched_barrier(0); \
    READ_AF(afA, b, 1, 0) \
    READ_BF(bf1, b, 1) \
    if (DS) { STAGE((b) ^ 1, 0, 1, (t) + 1) } \
    MFMA16(afB, bf0, 1) \
  }
#define PH3(b, t, DS) { \
    __builtin_amdgcn_s_barrier(); \
    READ_AF(afB, b, 1, 1) \
    if (DS) { STAGE((b) ^ 1, 1, 1, (t) + 1) } \
    MFMA16(afA, bf1, 0) \
  }
#define PH4(b, VM, RN) { \
    asm volatile("s_waitcnt vmcnt(" VM ")" ::: "memory"); \
    __builtin_amdgcn_s_barrier(); \
    __builtin_amdgcn_sched_barrier(0); \
    if (RN) { READ_AF(afA, (b) ^ 1, 0, 0) READ_BF(bf0, (b) ^ 1, 0) } \
    MFMA16(afB, bf1, 1) \
  }

  // Prologue: stage all of tile 0 (8 calls); wait its h0; read ph1 regs.
  STAGE(0, 0, 0, 0)   // A h0 (t0)
  STAGE(0, 1, 0, 0)   // B h0 (t0)
  STAGE(0, 0, 1, 0)   // A h1 (t0)
  STAGE(0, 1, 1, 0)   // B h1 (t0)
  asm volatile("s_waitcnt vmcnt(4)" ::: "memory");  // t0 h0 landed
  __builtin_amdgcn_s_barrier();
  __builtin_amdgcn_sched_barrier(0);
  READ_AF(afA, 0, 0, 0)
  READ_BF(bf0, 0, 0)

  for (int t = 0; t < NT - 1; ++t) {
    const int b = t & 1;
    PH1(b, t, true)
    PH2(b, t, "4", true)
    PH3(b, t, true)
    PH4(b, "4", true)
  }
  // last tile (t = NT-1, b = 1): no staging; drain.
  PH1(1, NT - 1, false)
  PH2(1, NT - 1, "0", false)
  PH3(1, NT - 1, false)
  PH4(1, "0", false)

  // Epilogue: C/D layout col=lane&15, row=(lane>>4)*4+reg
  const int colLane = lane & 15;
  const int rowGrp  = (lane >> 4) * 4;
#pragma unroll
  for (int fn = 0; fn < 4; ++fn) {
    const int col = bn * 256 + wn * 64 + fn * 16 + colLane;
    if (col < NREAL) {
      const float bias = fb[col] + bb[col] + lb[col];
#pragma unroll
      for (int m = 0; m < 8; ++m) {
        const int row0 = bm * 256 + wm * 128 + m * 16 + rowGrp;
#pragma unroll
        for (int r = 0; r < 4; ++r) {
          const float pre = acc[m][fn][r] + bias;
          const size_t oi = (size_t)(row0 + r) * NREAL + col;
          out[oi] = 0.7f * fmaxf(pre, 0.f) + 0.3f * selfact[oi];
        }
      }
    }
  }
#undef PH4
#undef PH3
#undef PH2
#undef PH1
#undef MFMA16
#undef READ_BF
#undef READ_AF
#undef STAGE
}

// ---------------------------------------------------------------------------
extern "C" void kernel_launch(void* const* d_in, const int* in_sizes, int n_in,
                              void* d_out, int out_size, void* d_ws,
                              size_t ws_size, hipStream_t stream) {
  const float* prev = (const float*)d_in[0];
  const float* selfa = (const float*)d_in[1];
  const float* nxt  = (const float*)d_in[2];
  const float* fW = (const float*)d_in[3];
  const float* fb = (const float*)d_in[4];
  const float* bW = (const float*)d_in[5];
  const float* bb = (const float*)d_in[6];
  const float* lW = (const float*)d_in[7];
  const float* lb = (const float*)d_in[8];
  float* out = (float*)d_out;

  unsigned short* Acat = (unsigned short*)d_ws;                 // 100.7 MB
  unsigned short* Wcat = Acat + (size_t)BATCH * KPAD;           // +25.2 MB

  pack_kernel<<<dim3(BATCH + NPAD, 3), 256, 0, stream>>>(
      prev, nxt, selfa, fW, bW, lW, Acat, Wcat);
  gemm_kernel<<<dim3(32 * 8), 512, 0, stream>>>(Acat, Wcat, fb, bb, lb,
                                                selfa, out);
}